// Round 3
// baseline (695.427 us; speedup 1.0000x reference)
//
#include <hip/hip_runtime.h>
#include <hip/hip_bf16.h>

#define H 1024
#define SEQ 2048
#define BATCH 32
#define MTOT (BATCH * SEQ)

#define BM 128
#define BN 128
#define BK 64

typedef __attribute__((ext_vector_type(4))) float f32x4;
typedef __attribute__((ext_vector_type(8))) __bf16 bf16x8;
typedef __attribute__((ext_vector_type(8))) unsigned short ushort8;

__device__ __forceinline__ unsigned short f2bf(float x) {
  __hip_bfloat16 h = __float2bfloat16(x);
  return __builtin_bit_cast(unsigned short, h);
}

__device__ __forceinline__ void gload_lds16(const void* g, void* l) {
  __builtin_amdgcn_global_load_lds(
      (const __attribute__((address_space(1))) unsigned int*)g,
      (__attribute__((address_space(3))) unsigned int*)l, 16, 0, 0);
}

// ---------------- kernel 1: We (fp32, k-major) -> WeT (bf16, n-major) ----------------
__global__ void we_transpose_kernel(const float* __restrict__ W,
                                    unsigned short* __restrict__ WeT) {
  __shared__ float t[64][65];
  const int bn = blockIdx.x * 64;  // n tile
  const int bk = blockIdx.y * 64;  // k tile
  const int tid = threadIdx.x;
  const int ln = tid & 63;
  const int lk = tid >> 6;
  const float* src = W + (size_t)(H + bk) * H + bn;  // We starts at row H
#pragma unroll
  for (int i = 0; i < 16; ++i) {
    int k = i * 4 + lk;
    t[k][ln] = src[(size_t)k * H + ln];
  }
  __syncthreads();
  const int n = tid >> 2;
  const int kg = tid & 3;
  ushort8 o0, o1;
#pragma unroll
  for (int j = 0; j < 8; ++j) o0[j] = f2bf(t[kg * 16 + j][n]);
#pragma unroll
  for (int j = 0; j < 8; ++j) o1[j] = f2bf(t[kg * 16 + 8 + j][n]);
  unsigned short* dst = WeT + (size_t)(bn + n) * H + bk + kg * 16;
  *(ushort8*)(dst) = o0;
  *(ushort8*)(dst + 8) = o1;
}

// ---------------- kernel 2: h_proj = hidden @ Wh + b_attn (fp32) ----------------
__global__ void hproj_kernel(const float* __restrict__ hidden,
                             const float* __restrict__ W,
                             const float* __restrict__ b_attn,
                             float* __restrict__ hproj) {
  __shared__ float h[H];
  const int b = blockIdx.y;
  const int n = blockIdx.x * 256 + threadIdx.x;
  for (int i = threadIdx.x; i < H; i += 256) h[i] = hidden[(size_t)b * H + i];
  __syncthreads();
  float acc = b_attn[n];
#pragma unroll 8
  for (int k = 0; k < H; ++k) acc = fmaf(h[k], W[(size_t)k * H + n], acc);
  hproj[(size_t)b * H + n] = acc;
}

// ---------------- kernel 3: fused GEMM + tanh + v-dot ----------------
// grid 4096: nb = bid&7 (fast, so A-panel siblings are concurrent -> L3 reuse),
// mt = bid>>3. Block: 256 thr = 4 waves (2x2), wave tile 64x64, mfma 16x16x32.
__global__ __launch_bounds__(256) void gemm_fused_kernel(
    const float* __restrict__ A,            // enc [MTOT][H] fp32
    const unsigned short* __restrict__ WeT, // [H][H] bf16 n-major
    const float* __restrict__ hproj,        // [BATCH][H]
    const float* __restrict__ v,            // [H]
    float* __restrict__ partials)           // [8][MTOT]
{
  __shared__ __align__(16) unsigned short As[BM * BK];
  __shared__ __align__(16) unsigned short Bs[BN * BK];
  __shared__ float red[2][BM];

  const int bid = blockIdx.x;
  const int nb = bid & 7;
  const int mt = bid >> 3;
  const int m0 = mt * BM;
  const int bb = m0 / SEQ;  // batch index, uniform per block (128 | 2048)

  const int tid = threadIdx.x;
  const int lane = tid & 63;
  const int w = tid >> 6;
  const int wm = w >> 1;
  const int wn = w & 1;

  // A staging: thread loads rows a_r0+16p, 16B chunk a_c (4 fp32)
  const int a_c = tid & 15;
  const int a_r0 = tid >> 4;
  const float* a_src = A + (size_t)(m0 + a_r0) * H + a_c * 4;
  char* AsB = (char*)As;
  char* BsB = (char*)Bs;

  // B staging via global_load_lds: linear LDS dest, inverse-swizzled global src
  const char* b_src[4];
  char* b_dst[4];
#pragma unroll
  for (int i = 0; i < 4; ++i) {
    int q = (w * 4 + i) * 64 + lane;     // 16B chunk id in tile
    int nl = q >> 3;                     // n row (8 chunks per 128B row)
    int c = (q & 7) ^ (nl & 7);          // inverse of read-side XOR swizzle
    b_src[i] = (const char*)WeT + ((size_t)(nb * 128 + nl) * H + c * 8) * 2;
    b_dst[i] = BsB + (w * 4 + i) * 1024; // wave-uniform base
  }

  f32x4 acc[4][4] = {};

  for (int ks = 0; ks < H / BK; ++ks) {
    // stage B (bf16 already) -- 4 x 1KB per wave
#pragma unroll
    for (int i = 0; i < 4; ++i) gload_lds16(b_src[i] + ks * 128, b_dst[i]);
    // stage A: fp32 load -> bf16 cvt -> swizzled ds_write (8B)
#pragma unroll
    for (int p = 0; p < 8; ++p) {
      const int row = a_r0 + p * 16;
      f32x4 f = *(const f32x4*)(a_src + (size_t)p * 16 * H + ks * 64);
      unsigned int lo = f2bf(f[0]) | ((unsigned int)f2bf(f[1]) << 16);
      unsigned int hi = f2bf(f[2]) | ((unsigned int)f2bf(f[3]) << 16);
      int boff = (row * 128 + a_c * 8) ^ ((row & 7) << 4);
      *(uint2*)(AsB + boff) = make_uint2(lo, hi);
    }
    __syncthreads();  // drains vmcnt (gll) + lgkmcnt

    bf16x8 af[4][2], bfr[4][2];
#pragma unroll
    for (int mi = 0; mi < 4; ++mi)
#pragma unroll
      for (int kk = 0; kk < 2; ++kk) {
        int row = wm * 64 + mi * 16 + (lane & 15);
        int c = kk * 4 + (lane >> 4);
        int off = (row * 128 + c * 16) ^ ((row & 7) << 4);
        af[mi][kk] = *(const bf16x8*)(AsB + off);
      }
#pragma unroll
    for (int ni = 0; ni < 4; ++ni)
#pragma unroll
      for (int kk = 0; kk < 2; ++kk) {
        int nl = wn * 64 + ni * 16 + (lane & 15);
        int c = kk * 4 + (lane >> 4);
        int off = (nl * 128 + c * 16) ^ ((nl & 7) << 4);
        bfr[ni][kk] = *(const bf16x8*)(BsB + off);
      }
#pragma unroll
    for (int kk = 0; kk < 2; ++kk)
#pragma unroll
      for (int mi = 0; mi < 4; ++mi)
#pragma unroll
        for (int ni = 0; ni < 4; ++ni)
          acc[mi][ni] = __builtin_amdgcn_mfma_f32_16x16x32_bf16(
              af[mi][kk], bfr[ni][kk], acc[mi][ni], 0, 0, 0);
    __syncthreads();
  }

  // epilogue: energy = tanh(C + hproj[col]); rowsum += energy * v[col]
  float rowsum[4][4];
#pragma unroll
  for (int mi = 0; mi < 4; ++mi)
#pragma unroll
    for (int i = 0; i < 4; ++i) rowsum[mi][i] = 0.f;

  const int colb = nb * 128 + wn * 64;
#pragma unroll
  for (int ni = 0; ni < 4; ++ni) {
    int colg = colb + ni * 16 + (lane & 15);
    float hp = hproj[(size_t)bb * H + colg];
    float vv = v[colg];
#pragma unroll
    for (int mi = 0; mi < 4; ++mi)
#pragma unroll
      for (int i = 0; i < 4; ++i)
        rowsum[mi][i] += tanhf(acc[mi][ni][i] + hp) * vv;
  }
  // reduce across the 16 lanes sharing a row group (C layout: col=lane&15)
#pragma unroll
  for (int mask = 1; mask <= 8; mask <<= 1)
#pragma unroll
    for (int mi = 0; mi < 4; ++mi)
#pragma unroll
      for (int i = 0; i < 4; ++i)
        rowsum[mi][i] += __shfl_xor(rowsum[mi][i], mask, 64);

  if ((lane & 15) == 0) {
    int rg = lane >> 4;
#pragma unroll
    for (int mi = 0; mi < 4; ++mi)
#pragma unroll
      for (int i = 0; i < 4; ++i)
        red[wn][wm * 64 + mi * 16 + rg * 4 + i] = rowsum[mi][i];
  }
  __syncthreads();
  if (tid < BM)
    partials[(size_t)nb * MTOT + m0 + tid] = red[0][tid] + red[1][tid];
}

// ---------------- kernel 4: softmax over S per batch ----------------
__global__ void softmax_kernel(const float* __restrict__ partials,
                               float* __restrict__ out) {
  const int b = blockIdx.x;
  const int tid = threadIdx.x;
  const int ln = tid & 63;
  const int wid = tid >> 6;
  __shared__ float r1[4], r2[4];
  float loc[8];
  float lmax = -3.4e38f;
#pragma unroll
  for (int j = 0; j < 8; ++j) {
    int s = j * 256 + tid;
    float acc = 0.f;
#pragma unroll
    for (int p = 0; p < 8; ++p)
      acc += partials[(size_t)p * MTOT + (size_t)b * SEQ + s];
    loc[j] = acc;
    lmax = fmaxf(lmax, acc);
  }
#pragma unroll
  for (int m = 1; m <= 32; m <<= 1) lmax = fmaxf(lmax, __shfl_xor(lmax, m, 64));
  if (ln == 0) r1[wid] = lmax;
  __syncthreads();
  const float gmax = fmaxf(fmaxf(r1[0], r1[1]), fmaxf(r1[2], r1[3]));
  float lsum = 0.f;
#pragma unroll
  for (int j = 0; j < 8; ++j) {
    loc[j] = expf(loc[j] - gmax);
    lsum += loc[j];
  }
#pragma unroll
  for (int m = 1; m <= 32; m <<= 1) lsum += __shfl_xor(lsum, m, 64);
  if (ln == 0) r2[wid] = lsum;
  __syncthreads();
  const float inv = 1.f / (r2[0] + r2[1] + r2[2] + r2[3]);
#pragma unroll
  for (int j = 0; j < 8; ++j)
    out[(size_t)b * SEQ + j * 256 + tid] = loc[j] * inv;
}

extern "C" void kernel_launch(void* const* d_in, const int* in_sizes, int n_in,
                              void* d_out, int out_size, void* d_ws, size_t ws_size,
                              hipStream_t stream) {
  const float* hidden = (const float*)d_in[0];
  const float* enc    = (const float*)d_in[1];
  const float* W      = (const float*)d_in[2];
  const float* b_attn = (const float*)d_in[3];
  const float* v      = (const float*)d_in[4];
  float* out = (float*)d_out;

  char* ws = (char*)d_ws;
  unsigned short* WeT = (unsigned short*)ws;                       // 2 MB
  float* hproj    = (float*)(ws + (2u << 20));                     // 128 KB
  float* partials = (float*)(ws + (2u << 20) + (128u << 10));      // 2 MB

  we_transpose_kernel<<<dim3(16, 16), 256, 0, stream>>>(W, WeT);
  hproj_kernel<<<dim3(4, BATCH), 256, 0, stream>>>(hidden, W, b_attn, hproj);
  gemm_fused_kernel<<<dim3(4096), 256, 0, stream>>>(enc, WeT, hproj, v, partials);
  softmax_kernel<<<dim3(BATCH), 256, 0, stream>>>(partials, out);
}

// Round 5
// 678.064 us; speedup vs baseline: 1.0256x; 1.0256x over previous
//
#include <hip/hip_runtime.h>
#include <hip/hip_bf16.h>

#define H 1024
#define SEQ 2048
#define BATCH 32
#define MTOT (BATCH * SEQ)

#define BM 128
#define BN 128
#define BK 64
#define KSTEPS (H / BK)   // 16
#define BUFB (BM * BK * 2) // bytes per LDS buffer (bf16)

typedef __attribute__((ext_vector_type(4))) float f32x4;
typedef __attribute__((ext_vector_type(8))) __bf16 bf16x8;
typedef __attribute__((ext_vector_type(8))) unsigned short ushort8;

__device__ __forceinline__ unsigned short f2bf(float x) {
  __hip_bfloat16 h = __float2bfloat16(x);
  return __builtin_bit_cast(unsigned short, h);
}

__device__ __forceinline__ void gload_lds16(const void* g, void* l) {
  __builtin_amdgcn_global_load_lds(
      (const __attribute__((address_space(1))) unsigned int*)g,
      (__attribute__((address_space(3))) unsigned int*)l, 16, 0, 0);
}

// ---------------- kernel 1: We (fp32, k-major) -> WeT (bf16, n-major) ----------------
__global__ void we_transpose_kernel(const float* __restrict__ W,
                                    unsigned short* __restrict__ WeT) {
  __shared__ float t[64][65];
  const int bn = blockIdx.x * 64;  // n tile
  const int bk = blockIdx.y * 64;  // k tile
  const int tid = threadIdx.x;
  const int ln = tid & 63;
  const int lk = tid >> 6;
  const float* src = W + (size_t)(H + bk) * H + bn;  // We starts at row H
#pragma unroll
  for (int i = 0; i < 16; ++i) {
    int k = i * 4 + lk;
    t[k][ln] = src[(size_t)k * H + ln];
  }
  __syncthreads();
  const int n = tid >> 2;
  const int kg = tid & 3;
  ushort8 o0, o1;
#pragma unroll
  for (int j = 0; j < 8; ++j) o0[j] = f2bf(t[kg * 16 + j][n]);
#pragma unroll
  for (int j = 0; j < 8; ++j) o1[j] = f2bf(t[kg * 16 + 8 + j][n]);
  unsigned short* dst = WeT + (size_t)(bn + n) * H + bk + kg * 16;
  *(ushort8*)(dst) = o0;
  *(ushort8*)(dst + 8) = o1;
}

// ---------------- kernel 2: h_proj = hidden @ Wh + b_attn (fp32) ----------------
__global__ void hproj_kernel(const float* __restrict__ hidden,
                             const float* __restrict__ W,
                             const float* __restrict__ b_attn,
                             float* __restrict__ hproj) {
  __shared__ float h[H];
  const int b = blockIdx.y;
  const int n = blockIdx.x * 256 + threadIdx.x;
  for (int i = threadIdx.x; i < H; i += 256) h[i] = hidden[(size_t)b * H + i];
  __syncthreads();
  float acc = b_attn[n];
#pragma unroll 8
  for (int k = 0; k < H; ++k) acc = fmaf(h[k], W[(size_t)k * H + n], acc);
  hproj[(size_t)b * H + n] = acc;
}

// ---------------- kernel 3: fused GEMM + tanh + v-dot ----------------
// XCD-grouped mapping: x=bid&7 (XCD via rr dispatch), i=bid>>3;
// nb=i&7, mt=x*64+(i>>3) -> all 8 nb-siblings of an M-panel on ONE XCD,
// dispatched within a 64-slot window (panel fetched once into that L2).
// Double-buffered LDS, prefetch-next-before-compute (T3-lite 2-phase).
__global__ __launch_bounds__(256) void gemm_fused_kernel(
    const float* __restrict__ A,            // enc [MTOT][H] fp32
    const unsigned short* __restrict__ WeT, // [H][H] bf16 n-major
    const float* __restrict__ hproj,        // [BATCH][H]
    const float* __restrict__ v,            // [H]
    float* __restrict__ partials)           // [8][MTOT]
{
  __shared__ __align__(16) unsigned short As[2][BM * BK];
  __shared__ __align__(16) unsigned short Bs[2][BN * BK];
  __shared__ float red[2][BM];

  const int d = blockIdx.x;
  const int x = d & 7;        // XCD (hw round-robin over dispatch index)
  const int ii = d >> 3;      // 0..511 within XCD
  const int nb = ii & 7;
  const int mt = x * 64 + (ii >> 3);
  const int m0 = mt * BM;
  const int bb = m0 / SEQ;    // batch index, uniform per block

  const int tid = threadIdx.x;
  const int lane = tid & 63;
  const int w = tid >> 6;
  const int wm = w >> 1;
  const int wn = w & 1;

  // A staging: thread loads rows a_r0+16p, 16B chunk a_c (4 fp32)
  const int a_c = tid & 15;
  const int a_r0 = tid >> 4;
  const float* a_src = A + (size_t)(m0 + a_r0) * H + a_c * 4;
  char* AsB = (char*)As;
  char* BsB = (char*)Bs;
  const int a_boff = (a_r0 * 128 + a_c * 8) ^ ((a_r0 & 7) << 4);  // row p=0

  // B staging via global_load_lds: linear LDS dest, inverse-swizzled global src
  const char* bsrc[4];
  int bdst[4];
#pragma unroll
  for (int i = 0; i < 4; ++i) {
    int q = (w * 4 + i) * 64 + lane;     // 16B chunk id in tile
    int nl = q >> 3;                     // n row (8 chunks per 128B row)
    int c = (q & 7) ^ (nl & 7);          // inverse of read-side XOR swizzle
    bsrc[i] = (const char*)WeT + ((size_t)(nb * 128 + nl) * H + c * 8) * 2;
    bdst[i] = (w * 4 + i) * 1024;        // wave-uniform base (per buffer)
  }

  f32x4 acc[4][4] = {};

  // ---- prologue: stage tile 0 into buffer 0 ----
#pragma unroll
  for (int i = 0; i < 4; ++i) gload_lds16(bsrc[i], BsB + bdst[i]);
#pragma unroll
  for (int p = 0; p < 8; ++p) {
    f32x4 f = *(const f32x4*)(a_src + (size_t)p * 16 * H);
    unsigned int lo = f2bf(f[0]) | ((unsigned int)f2bf(f[1]) << 16);
    unsigned int hi = f2bf(f[2]) | ((unsigned int)f2bf(f[3]) << 16);
    *(uint2*)(AsB + ((a_boff + p * 16 * 128) ^ 0)) = make_uint2(lo, hi);
  }
  __syncthreads();

#pragma unroll 2
  for (int ks = 0; ks < KSTEPS; ++ks) {
    const int cur = ks & 1;
    char* curA = AsB + cur * BUFB;
    char* curB = BsB + cur * BUFB;
    char* nxtA = AsB + (cur ^ 1) * BUFB;
    char* nxtB = BsB + (cur ^ 1) * BUFB;
    const bool pf = (ks + 1) < KSTEPS;

    // issue next-tile staging FIRST (latency hides under ds_read + MFMA)
    f32x4 fa[8];
    if (pf) {
#pragma unroll
      for (int p = 0; p < 8; ++p)
        fa[p] = *(const f32x4*)(a_src + (size_t)p * 16 * H + (ks + 1) * 64);
#pragma unroll
      for (int i = 0; i < 4; ++i)
        gload_lds16(bsrc[i] + (size_t)(ks + 1) * 128, nxtB + bdst[i]);
    }

    // ds_read current fragments
    bf16x8 af[4][2], bfr[4][2];
#pragma unroll
    for (int mi = 0; mi < 4; ++mi)
#pragma unroll
      for (int kk = 0; kk < 2; ++kk) {
        int row = wm * 64 + mi * 16 + (lane & 15);
        int c = kk * 4 + (lane >> 4);
        int off = (row * 128 + c * 16) ^ ((row & 7) << 4);
        af[mi][kk] = *(const bf16x8*)(curA + off);
      }
#pragma unroll
    for (int ni = 0; ni < 4; ++ni)
#pragma unroll
      for (int kk = 0; kk < 2; ++kk) {
        int nl = wn * 64 + ni * 16 + (lane & 15);
        int c = kk * 4 + (lane >> 4);
        int off = (nl * 128 + c * 16) ^ ((nl & 7) << 4);
        bfr[ni][kk] = *(const bf16x8*)(curB + off);
      }

    // write next A tile (cvt arrives under the MFMA cluster's shadow)
    if (pf) {
#pragma unroll
      for (int p = 0; p < 8; ++p) {
        unsigned int lo = f2bf(fa[p][0]) | ((unsigned int)f2bf(fa[p][1]) << 16);
        unsigned int hi = f2bf(fa[p][2]) | ((unsigned int)f2bf(fa[p][3]) << 16);
        int row = a_r0 + p * 16;
        int boff = (row * 128 + a_c * 8) ^ ((row & 7) << 4);
        *(uint2*)(nxtA + boff) = make_uint2(lo, hi);
      }
    }

#pragma unroll
    for (int kk = 0; kk < 2; ++kk)
#pragma unroll
      for (int mi = 0; mi < 4; ++mi)
#pragma unroll
        for (int ni = 0; ni < 4; ++ni)
          acc[mi][ni] = __builtin_amdgcn_mfma_f32_16x16x32_bf16(
              af[mi][kk], bfr[ni][kk], acc[mi][ni], 0, 0, 0);
    __syncthreads();
  }

  // epilogue: energy = tanh(C + hproj[col]); rowsum += energy * v[col]
  float rowsum[4][4];
#pragma unroll
  for (int mi = 0; mi < 4; ++mi)
#pragma unroll
    for (int i = 0; i < 4; ++i) rowsum[mi][i] = 0.f;

  const int colb = nb * 128 + wn * 64;
#pragma unroll
  for (int ni = 0; ni < 4; ++ni) {
    int colg = colb + ni * 16 + (lane & 15);
    float hp = hproj[(size_t)bb * H + colg];
    float vv = v[colg];
#pragma unroll
    for (int mi = 0; mi < 4; ++mi)
#pragma unroll
      for (int i = 0; i < 4; ++i)
        rowsum[mi][i] += tanhf(acc[mi][ni][i] + hp) * vv;
  }
  // reduce across the 16 lanes sharing a row group (C layout: col=lane&15)
#pragma unroll
  for (int mask = 1; mask <= 8; mask <<= 1)
#pragma unroll
    for (int mi = 0; mi < 4; ++mi)
#pragma unroll
      for (int i = 0; i < 4; ++i)
        rowsum[mi][i] += __shfl_xor(rowsum[mi][i], mask, 64);

  if ((lane & 15) == 0) {
    int rg = lane >> 4;
#pragma unroll
    for (int mi = 0; mi < 4; ++mi)
#pragma unroll
      for (int i = 0; i < 4; ++i)
        red[wn][wm * 64 + mi * 16 + rg * 4 + i] = rowsum[mi][i];
  }
  __syncthreads();
  if (tid < BM)
    partials[(size_t)nb * MTOT + m0 + tid] = red[0][tid] + red[1][tid];
}

// ---------------- kernel 4: softmax over S per batch ----------------
__global__ void softmax_kernel(const float* __restrict__ partials,
                               float* __restrict__ out) {
  const int b = blockIdx.x;
  const int tid = threadIdx.x;
  const int ln = tid & 63;
  const int wid = tid >> 6;
  __shared__ float r1[4], r2[4];
  float loc[8];
  float lmax = -3.4e38f;
#pragma unroll
  for (int j = 0; j < 8; ++j) {
    int s = j * 256 + tid;
    float acc = 0.f;
#pragma unroll
    for (int p = 0; p < 8; ++p)
      acc += partials[(size_t)p * MTOT + (size_t)b * SEQ + s];
    loc[j] = acc;
    lmax = fmaxf(lmax, acc);
  }
#pragma unroll
  for (int m = 1; m <= 32; m <<= 1) lmax = fmaxf(lmax, __shfl_xor(lmax, m, 64));
  if (ln == 0) r1[wid] = lmax;
  __syncthreads();
  const float gmax = fmaxf(fmaxf(r1[0], r1[1]), fmaxf(r1[2], r1[3]));
  float lsum = 0.f;
#pragma unroll
  for (int j = 0; j < 8; ++j) {
    loc[j] = expf(loc[j] - gmax);
    lsum += loc[j];
  }
#pragma unroll
  for (int m = 1; m <= 32; m <<= 1) lsum += __shfl_xor(lsum, m, 64);
  if (ln == 0) r2[wid] = lsum;
  __syncthreads();
  const float inv = 1.f / (r2[0] + r2[1] + r2[2] + r2[3]);
#pragma unroll
  for (int j = 0; j < 8; ++j)
    out[(size_t)b * SEQ + j * 256 + tid] = loc[j] * inv;
}

extern "C" void kernel_launch(void* const* d_in, const int* in_sizes, int n_in,
                              void* d_out, int out_size, void* d_ws, size_t ws_size,
                              hipStream_t stream) {
  const float* hidden = (const float*)d_in[0];
  const float* enc    = (const float*)d_in[1];
  const float* W      = (const float*)d_in[2];
  const float* b_attn = (const float*)d_in[3];
  const float* v      = (const float*)d_in[4];
  float* out = (float*)d_out;

  char* ws = (char*)d_ws;
  unsigned short* WeT = (unsigned short*)ws;                       // 2 MB
  float* hproj    = (float*)(ws + (2u << 20));                     // 128 KB
  float* partials = (float*)(ws + (2u << 20) + (128u << 10));      // 2 MB

  we_transpose_kernel<<<dim3(16, 16), 256, 0, stream>>>(W, WeT);
  hproj_kernel<<<dim3(4, BATCH), 256, 0, stream>>>(hidden, W, b_attn, hproj);
  gemm_fused_kernel<<<dim3(4096), 256, 0, stream>>>(enc, WeT, hproj, v, partials);
  softmax_kernel<<<dim3(BATCH), 256, 0, stream>>>(partials, out);
}